// Round 16
// baseline (173.108 us; speedup 1.0000x reference)
//
#include <hip/hip_runtime.h>

#define T_STEPS 144000
#define HDIM 128
#define G4 512
#define NB 10
#define CH 16
#define EPS 1e-2f
#define WIN 2
#define SENT 0x7fffffff
#define RING0 4096
#define R0M (RING0-1)
#define RING1 1024
#define R1M (RING1-1)
#define NBLK 256

typedef _Float16 h2f __attribute__((ext_vector_type(2)));

__device__ __forceinline__ float fdot2_(h2f a, h2f b, float c){
#if __has_builtin(__builtin_amdgcn_fdot2)
  return __builtin_amdgcn_fdot2(a, b, c, false);
#else
  float d;
  asm("v_dot2_f32_f16 %0, %1, %2, %3" : "=v"(d) : "v"(a), "v"(b), "v"(c));
  return d;
#endif
}
__device__ __forceinline__ h2f pack2(float x, float y){ h2f r; r[0]=(_Float16)x; r[1]=(_Float16)y; return r; }
__device__ __forceinline__ h2f bc(float f){ return __builtin_bit_cast(h2f, f); }

__device__ __forceinline__ float sigf(float x){ return 1.f/(1.f+__expf(-x)); }
__device__ __forceinline__ float tanh_(float x){
  float e2 = __expf(-2.f*fabsf(x));
  float r = (1.f - e2)/(1.f + e2);
  return copysignf(r, x);
}

// LDS-only barrier: skips the vmcnt(0) drain __syncthreads() would do.
#define FAST_BAR() do { \
  asm volatile("s_waitcnt lgkmcnt(0)" ::: "memory"); \
  __builtin_amdgcn_s_barrier(); \
  asm volatile("" ::: "memory"); \
} while (0)

// 8-accumulator fp16 dot2 matvec body (128-dim row dot)
#define MATVEC8(WH, H4, A0INIT)                                   \
  float a0 = (A0INIT), a1 = 0.f, a2 = 0.f, a3 = 0.f,              \
        a4 = 0.f, a5 = 0.f, a6 = 0.f, a7 = 0.f;                   \
  _Pragma("unroll")                                               \
  for (int k = 0; k < 8; k++) {                                   \
    float4 hv0 = (H4)[2*k], hv1 = (H4)[2*k+1];                    \
    a0 = fdot2_((WH)[8*k+0], bc(hv0.x), a0);                      \
    a1 = fdot2_((WH)[8*k+1], bc(hv0.y), a1);                      \
    a2 = fdot2_((WH)[8*k+2], bc(hv0.z), a2);                      \
    a3 = fdot2_((WH)[8*k+3], bc(hv0.w), a3);                      \
    a4 = fdot2_((WH)[8*k+4], bc(hv1.x), a4);                      \
    a5 = fdot2_((WH)[8*k+5], bc(hv1.y), a5);                      \
    a6 = fdot2_((WH)[8*k+6], bc(hv1.z), a6);                      \
    a7 = fdot2_((WH)[8*k+7], bc(hv1.w), a7);                      \
  }                                                               \
  float pre = ((a0+a1)+(a2+a3)) + ((a4+a5)+(a6+a7));

// flags (ints): line0: [0,1]=prog0 [2,3]=T0p1 [4..7]=progP [8,9]=progC [10,11]=T1p1
//                      [12,13]=progH [16]=prepCnt
//               line1 (byte 128+): [32,33]=headDone  <- own cache line, written ONCE
__global__ __launch_bounds__(512) void k_all(
    const float* __restrict__ x, const float* __restrict__ w1, const float* __restrict__ b1,
    const float* __restrict__ w2, const float* __restrict__ b2,
    const float* __restrict__ w_ih0, const float* __restrict__ b_ih0, const float* __restrict__ b_hh0,
    const float* __restrict__ w_hh0, const float* __restrict__ w_hh1,
    const float* __restrict__ w_ih1,
    const float* __restrict__ b_ih1, const float* __restrict__ b_hh1,
    const float* __restrict__ w_out, const float* __restrict__ b_out,
    int* __restrict__ flags, float* __restrict__ outst, float* __restrict__ xproj0,
    float* __restrict__ hs0, float* __restrict__ h1s,
    float* __restrict__ xproj1, float* __restrict__ out)
{
  __shared__ __align__(16) float gls[G4];
  __shared__ __align__(16) _Float16 hls16[HDIM];
  __shared__ __align__(16) float s0ls[CH*HDIM];
  __shared__ float lat1[2][64];
  __shared__ __align__(16) float lat2[2][128];
  __shared__ int okw[2];
  __shared__ int ipc[4];
  const int blk = blockIdx.x;
  const int j = threadIdx.x;
  const int gt = j >> 7;
  int* prog0 = flags + 0; int* T0p1 = flags + 2; int* progP = flags + 4;
  int* progC = flags + 8; int* T1p1 = flags + 10; int* progH = flags + 12;
  int* pcnt = flags + 16; int* hdone = flags + 32;

  if (blk < 32) {
    // ===================== prep: encoder MLP + xproj0 (then fill) =====================
    if (j < 128) {
      int b = j >> 6, jj = j & 63;
      float a = b1[jj];
      #pragma unroll
      for (int k = 0; k < 16; k++) a += x[b*16+k] * w1[jj*16+k];
      lat1[b][jj] = fmaxf(a, 0.f);
    }
    __syncthreads();
    if (j < 256) {
      int b = j >> 7, jj = j & 127;
      float a = b2[jj];
      #pragma unroll
      for (int k = 0; k < 64; k++) a += lat1[b][k] * w2[jj*64+k];
      lat2[b][jj] = fmaxf(a, 0.f);
    }
    __syncthreads();
    if (j < 256) {
      const int rid = blk*32 + (j >> 3);        // 0..1023
      const int b = rid >> 9, r = rid & 511, l8 = j & 7;
      const float4* wv = (const float4*)(w_ih0 + r*128 + l8*16);
      const float4* lv = (const float4*)(&lat2[b][l8*16]);
      float a = 0.f;
      #pragma unroll
      for (int q = 0; q < 4; q++) {
        float4 w = wv[q], l = lv[q];
        a += w.x*l.x + w.y*l.y + w.z*l.z + w.w*l.w;
      }
      a += __shfl_xor(a, 1, 8);
      a += __shfl_xor(a, 2, 8);
      a += __shfl_xor(a, 4, 8);
      if (l8 == 0) xproj0[b*G4 + r] = a + b_ih0[r] + b_hh0[r];
    }
    __syncthreads();                            // drain xproj0 stores
    if (j == 0) __hip_atomic_fetch_add(pcnt, 1, __ATOMIC_RELEASE, __HIP_MEMORY_SCOPE_AGENT);
  } else if (blk < 34) {
    // ===================== layer-0 producer =====================
    const int b = blk - 32;
    h2f wh[64];
    {
      const float4* wr = (const float4*)(w_hh0 + j*128);
      #pragma unroll
      for (int k = 0; k < 32; k++) {
        float4 w = wr[k];
        wh[2*k]   = pack2(w.x, w.y);
        wh[2*k+1] = pack2(w.z, w.w);
      }
    }
    if (j == 0) {
      while (__hip_atomic_load(pcnt, __ATOMIC_ACQUIRE, __HIP_MEMORY_SCOPE_AGENT) < 32)
        __builtin_amdgcn_s_sleep(2);
    }
    __syncthreads();
    const float xp = xproj0[b*G4 + j];
    float* hb = hs0 + (size_t)b * RING0 * HDIM;
    if (j < HDIM) hls16[j] = (_Float16)0.f;
    float c = 0.f, hp = 0.f;
    int cnt = 0;
    __syncthreads();
    int t = 0;
    for (; t < T_STEPS; ++t) {
      const float4* h4 = (const float4*)hls16;
      MATVEC8(wh, h4, xp)
      gls[j] = (gt == 2) ? tanh_(pre) : sigf(pre);
      FAST_BAR();                                        // bar1 (LDS-only)
      float nh_reg = 0.f;
      if (j < HDIM) {
        float ii = gls[j], ff = gls[128+j], gg = gls[256+j], oo = gls[384+j];
        float nc = ff*c + ii*gg;
        float nh = oo*tanh_(nc);
        bool ok = fabsf(nh-hp) <= EPS && fabsf(nc-c) <= EPS*fmaxf(1.f, fabsf(nc));
        c = nc; hp = nh;
        hls16[j] = (_Float16)nh;
        nh_reg = nh;
        unsigned long long bal = __ballot(ok);
        if ((j & 63) == 0) okw[j >> 6] = (bal == ~0ull) ? 1 : 0;
      }
      FAST_BAR();                                        // bar2 (LDS-only)
      if (j < HDIM) hb[(t & R0M)*HDIM + j] = nh_reg;     // drained at chunk barrier
      cnt = (okw[0] && okw[1]) ? cnt + 1 : 0;
      bool conv = (cnt >= WIN);
      if (((t & (CH-1)) == (CH-1)) && !conv) {
        __syncthreads();                                 // FULL: drains chunk's hb stores
        if (j == 0) {
          __hip_atomic_store(&prog0[b], t+1, __ATOMIC_RELEASE, __HIP_MEMORY_SCOPE_AGENT);
          for (;;) {
            int lo = __hip_atomic_load(&progP[2*b+0], __ATOMIC_ACQUIRE, __HIP_MEMORY_SCOPE_AGENT);
            int hi = __hip_atomic_load(&progP[2*b+1], __ATOMIC_ACQUIRE, __HIP_MEMORY_SCOPE_AGENT);
            int mp = min(lo, hi);
            if ((t + 1 + CH) - mp <= RING0) break;
            __builtin_amdgcn_s_sleep(2);
          }
        }
      }
      if (conv) { ++t; break; }
    }
    __syncthreads();                                     // FULL: drain final stores
    if (j == 0) {
      __hip_atomic_store(&prog0[b], t, __ATOMIC_RELEASE, __HIP_MEMORY_SCOPE_AGENT);
      __hip_atomic_store(&T0p1[b], t+1, __ATOMIC_RELEASE, __HIP_MEMORY_SCOPE_AGENT);
    }
  } else if (blk < 38) {
    // ===================== projector (4 blocks: 2 per batch, reg weights, f32) =====================
    const int pblk = blk - 34;
    const int b = pblk >> 1, half = pblk & 1;
    const int lr = j >> 1, hf2 = j & 1;
    const int row = half*256 + lr;
    float4 wp[16];
    const float4* wr = (const float4*)(w_ih1 + row*128 + hf2*64);
    #pragma unroll
    for (int k = 0; k < 16; k++) wp[k] = wr[k];
    const float biasr = (hf2 == 0) ? (b_ih1[row] + b_hh1[row]) : 0.f;
    const float* hb = hs0 + (size_t)b * RING0 * HDIM;
    float* xp1b = xproj1 + (size_t)b * RING1 * G4;
    int t = 0;
    for (;;) {
      if (j == 0) {
        int av, tv;
        for (;;) {
          av = __hip_atomic_load(&prog0[b], __ATOMIC_ACQUIRE, __HIP_MEMORY_SCOPE_AGENT);
          tv = __hip_atomic_load(&T0p1[b], __ATOMIC_ACQUIRE, __HIP_MEMORY_SCOPE_AGENT);
          int T0v = (tv == 0) ? SENT : tv - 1;
          if (T0v != SENT && t >= T0v) break;
          int need = t + CH; if (T0v != SENT && T0v < need) need = T0v;
          int cons = __hip_atomic_load(&progC[b], __ATOMIC_ACQUIRE, __HIP_MEMORY_SCOPE_AGENT);
          if (av >= need && need <= cons + RING1) break;
          __builtin_amdgcn_s_sleep(2);
        }
        ipc[0] = av; ipc[1] = tv;
      }
      __syncthreads();
      int av = ipc[0], tv = ipc[1];
      int T0v = (tv == 0) ? SENT : tv - 1;
      if (T0v != SENT && t >= T0v) break;
      int lim = (T0v != SENT && T0v < av) ? T0v : av;
      int C = min(CH, lim - t);
      for (int idx = j; idx < CH*HDIM; idx += 512) {
        int cc = idx >> 7, lane = idx & 127;
        float v = 0.f;
        if (cc < C) v = hb[((t + cc) & R0M)*HDIM + lane];
        s0ls[idx] = v;
      }
      __syncthreads();
      float xpa[CH];
      #pragma unroll
      for (int cc = 0; cc < CH; cc++) xpa[cc] = 0.f;
      #pragma unroll
      for (int k = 0; k < 16; k++) {
        float4 w = wp[k];
        const float4* sp = ((const float4*)s0ls) + hf2*16 + k;
        #pragma unroll
        for (int cc = 0; cc < CH; cc++) {
          if (cc >= C) break;
          float4 sv = sp[cc*32];
          xpa[cc] += w.x*sv.x + w.y*sv.y + w.z*sv.z + w.w*sv.w;
        }
      }
      #pragma unroll
      for (int cc = 0; cc < CH; cc++) {
        if (cc >= C) break;
        float v = xpa[cc] + biasr;
        v += __shfl_xor(v, 1, 2);
        if (hf2 == 0) xp1b[((t + cc) & R1M)*G4 + row] = v;
      }
      __syncthreads();                                   // FULL: drains xp1b stores
      if (j == 0) {
        __hip_atomic_store(&progP[2*b + half], t + C, __ATOMIC_RELEASE, __HIP_MEMORY_SCOPE_AGENT);
      }
      t += C;
    }
  } else if (blk < 40) {
    // ===================== layer-1 consumer =====================
    const int b = blk - 38;
    h2f wh[64];
    {
      const float4* wr = (const float4*)(w_hh1 + j*128);
      #pragma unroll
      for (int k = 0; k < 32; k++) {
        float4 w = wr[k];
        wh[2*k]   = pack2(w.x, w.y);
        wh[2*k+1] = pack2(w.z, w.w);
      }
    }
    const float* hb = hs0 + (size_t)b * RING0 * HDIM;
    float* h1b = h1s + (size_t)b * RING0 * HDIM;
    const float* xp1b = xproj1 + (size_t)b * RING1 * G4;
    if (j < HDIM) hls16[j] = (_Float16)0.f;
    float c = 0.f, hp = 0.f;
    int cnt = 0;
    __syncthreads();
    int t = 0, T0fin = T_STEPS;

    // -------- Phase A: t < T0, input from xproj1 ring --------
    for (;;) {
      if (j == 0) {
        int pv, tv;
        for (;;) {
          int lo = __hip_atomic_load(&progP[2*b+0], __ATOMIC_ACQUIRE, __HIP_MEMORY_SCOPE_AGENT);
          int hi = __hip_atomic_load(&progP[2*b+1], __ATOMIC_ACQUIRE, __HIP_MEMORY_SCOPE_AGENT);
          pv = min(lo, hi);
          tv = __hip_atomic_load(&T0p1[b], __ATOMIC_ACQUIRE, __HIP_MEMORY_SCOPE_AGENT);
          int T0v = (tv == 0) ? SENT : tv - 1;
          if (T0v != SENT && t >= T0v) break;
          int need = t + CH; if (T0v != SENT && T0v < need) need = T0v;
          int ph = __hip_atomic_load(&progH[b], __ATOMIC_ACQUIRE, __HIP_MEMORY_SCOPE_AGENT);
          if (pv >= need && need - ph <= RING0) break;
          __builtin_amdgcn_s_sleep(2);
        }
        ipc[2] = pv; ipc[3] = tv;
      }
      __syncthreads();
      int pv = ipc[2], tv = ipc[3];
      int T0v = (tv == 0) ? SENT : tv - 1;
      if (T0v != SENT && t >= T0v) { T0fin = T0v; break; }
      int lim = (T0v != SENT && T0v < pv) ? T0v : pv;
      int C = min(CH, lim - t);
      float xpa[CH];
      #pragma unroll
      for (int cc = 0; cc < CH; cc++) {
        if (cc >= C) break;
        xpa[cc] = xp1b[((t + cc) & R1M)*G4 + j];
      }
      for (int cc = 0; cc < C; cc++) {
        const float4* h4 = (const float4*)hls16;
        MATVEC8(wh, h4, xpa[cc])
        gls[j] = (gt == 2) ? tanh_(pre) : sigf(pre);
        FAST_BAR();                                      // bar1 (LDS-only)
        float nh_reg = 0.f;
        if (j < HDIM) {
          float ii = gls[j], ff = gls[128+j], gg = gls[256+j], oo = gls[384+j];
          float nc = ff*c + ii*gg;
          float nh = oo*tanh_(nc);
          c = nc; hp = nh;
          hls16[j] = (_Float16)nh;
          nh_reg = nh;
        }
        FAST_BAR();                                      // bar2 (LDS-only)
        if (j < HDIM) h1b[((t + cc) & R0M)*HDIM + j] = nh_reg;  // drained at chunk barrier
      }
      __syncthreads();                                   // FULL: drains chunk's h1 stores
      if (j == 0) {
        __hip_atomic_store(&progC[b], t + C, __ATOMIC_RELEASE, __HIP_MEMORY_SCOPE_AGENT);
      }
      t += C;
    }

    // -------- Phase B: constant input, convergence detect --------
    if (T0fin < T_STEPS) {
      if (j < HDIM) s0ls[j] = hb[((T0fin-1) & R0M)*HDIM + j];
      __syncthreads();
      float xb = b_ih1[j] + b_hh1[j];
      {
        const float4* wi = (const float4*)(w_ih1 + j*128);
        const float4* s04 = (const float4*)s0ls;
        #pragma unroll
        for (int k = 0; k < 32; k++) {
          float4 w = wi[k], sv = s04[k];
          xb += w.x*sv.x + w.y*sv.y + w.z*sv.z + w.w*sv.w;
        }
      }
      for (; t < T_STEPS; ++t) {
        const float4* h4 = (const float4*)hls16;
        MATVEC8(wh, h4, xb)
        gls[j] = (gt == 2) ? tanh_(pre) : sigf(pre);
        FAST_BAR();                                      // bar1 (LDS-only)
        float nh_reg = 0.f;
        if (j < HDIM) {
          float ii = gls[j], ff = gls[128+j], gg = gls[256+j], oo = gls[384+j];
          float nc = ff*c + ii*gg;
          float nh = oo*tanh_(nc);
          bool ok = fabsf(nh-hp) <= EPS && fabsf(nc-c) <= EPS*fmaxf(1.f, fabsf(nc));
          c = nc; hp = nh;
          hls16[j] = (_Float16)nh;
          nh_reg = nh;
          unsigned long long bal = __ballot(ok);
          if ((j & 63) == 0) okw[j >> 6] = (bal == ~0ull) ? 1 : 0;
        }
        FAST_BAR();                                      // bar2 (LDS-only)
        if (j < HDIM) h1b[(t & R0M)*HDIM + j] = nh_reg;  // drained at chunk barrier
        cnt = (okw[0] && okw[1]) ? cnt + 1 : 0;
        bool conv = (cnt >= WIN);
        if (((t & (CH-1)) == (CH-1)) && !conv) {
          __syncthreads();                               // FULL: drains chunk's h1 stores
          if (j == 0) {
            __hip_atomic_store(&progC[b], t+1, __ATOMIC_RELEASE, __HIP_MEMORY_SCOPE_AGENT);
            for (;;) {
              int ph = __hip_atomic_load(&progH[b], __ATOMIC_ACQUIRE, __HIP_MEMORY_SCOPE_AGENT);
              if ((t + 1 + CH) - ph <= RING0) break;
              __builtin_amdgcn_s_sleep(2);
            }
          }
        }
        if (conv) { ++t; break; }
      }
    }
    __syncthreads();                                     // FULL: drain final h1 stores
    if (j == 0) {
      __hip_atomic_store(&progC[b], t, __ATOMIC_RELEASE, __HIP_MEMORY_SCOPE_AGENT);
      __hip_atomic_store(&T1p1[b], t + 1, __ATOMIC_RELEASE, __HIP_MEMORY_SCOPE_AGENT);
    }
  } else if (blk < 42) {
    // ===================== head (2 blocks): out = w_out . h1 + b_out =====================
    const int b = blk - 40;
    const float* h1b = h1s + (size_t)b * RING0 * HDIM;
    float* outb = out + (size_t)b * T_STEPS * NB;
    const int n = (j < 160) ? (j >> 4) : 0;   // band 0..9
    const int cc16 = j & 15;                  // step-in-chunk
    float4 wo4[32];
    if (j < 160) {
      const float4* wv = (const float4*)(w_out + n*HDIM);
      #pragma unroll
      for (int k = 0; k < 32; k++) wo4[k] = wv[k];
    }
    const float bo = (j < 160) ? b_out[n] : 0.f;
    int t = 0, T1fin = -1;
    for (;;) {
      if (j == 0) {
        int pc, tv;
        for (;;) {
          pc = __hip_atomic_load(&progC[b], __ATOMIC_ACQUIRE, __HIP_MEMORY_SCOPE_AGENT);
          tv = __hip_atomic_load(&T1p1[b], __ATOMIC_ACQUIRE, __HIP_MEMORY_SCOPE_AGENT);
          if (tv != 0 || pc >= t + 1) break;
          __builtin_amdgcn_s_sleep(2);
        }
        ipc[0] = pc; ipc[1] = tv;
      }
      __syncthreads();
      int pc = ipc[0], tv = ipc[1];
      int T1v = (tv == 0) ? SENT : tv - 1;
      int lim = (T1v != SENT && T1v < pc) ? T1v : pc;
      while (t < lim) {
        int C = min(CH, lim - t);
        if (j < 160 && cc16 < C) {
          const float4* hv4 = (const float4*)(h1b + (size_t)((t + cc16) & R0M)*HDIM);
          float a0 = 0.f, a1 = 0.f, a2 = 0.f, a3 = 0.f;
          #pragma unroll
          for (int k = 0; k < 32; k++) {
            float4 h = hv4[k], w = wo4[k];
            a0 += w.x*h.x; a1 += w.y*h.y; a2 += w.z*h.z; a3 += w.w*h.w;
          }
          outb[(size_t)(t + cc16)*NB + n] = (a0+a1)+(a2+a3) + bo;
        }
        t += C;
      }
      __syncthreads();
      if (j == 0) __hip_atomic_store(&progH[b], t, __ATOMIC_RELEASE, __HIP_MEMORY_SCOPE_AGENT);
      if (T1v != SENT && t >= T1v) { T1fin = T1v; break; }
    }
    // outstar from h1[T1-1]
    if (j < 10) {
      const float4* hv4 = (const float4*)(h1b + (size_t)((T1fin - 1) & R0M)*HDIM);
      const float4* wv = (const float4*)(w_out + j*HDIM);
      float a0 = 0.f, a1 = 0.f, a2 = 0.f, a3 = 0.f;
      #pragma unroll
      for (int k = 0; k < 32; k++) {
        float4 h = hv4[k], w = wv[k];
        a0 += w.x*h.x; a1 += w.y*h.y; a2 += w.z*h.z; a3 += w.w*h.w;
      }
      outst[b*NB + j] = (a0+a1)+(a2+a3) + b_out[j];
    }
    __syncthreads();                                     // drain out/outst stores
    if (j == 0) __hip_atomic_store(&hdone[b], 1, __ATOMIC_RELEASE, __HIP_MEMORY_SCOPE_AGENT);
  }
  // blocks 42..255 fall through directly to the fill

  // ===================== common fill: out[t >= T1] = out* (all blocks) =====================
  if (j == 0) {
    while (!(__hip_atomic_load(&hdone[0], __ATOMIC_ACQUIRE, __HIP_MEMORY_SCOPE_AGENT) &&
             __hip_atomic_load(&hdone[1], __ATOMIC_ACQUIRE, __HIP_MEMORY_SCOPE_AGENT)))
      __builtin_amdgcn_s_sleep(32);
    ipc[0] = __hip_atomic_load(&T1p1[0], __ATOMIC_ACQUIRE, __HIP_MEMORY_SCOPE_AGENT);
    ipc[1] = __hip_atomic_load(&T1p1[1], __ATOMIC_ACQUIRE, __HIP_MEMORY_SCOPE_AGENT);
  }
  __syncthreads();
  const int T1a = ipc[0] - 1, T1b = ipc[1] - 1;
  const int total = 2*T_STEPS*NB;
  for (int idx = blk*512 + j; idx < total; idx += NBLK*512) {
    int n = idx % NB;
    int bt = idx / NB;
    int t = bt % T_STEPS;
    int b = bt / T_STEPS;
    if (t >= (b ? T1b : T1a)) out[idx] = outst[b*NB + n];
  }
}

extern "C" void kernel_launch(void* const* d_in, const int* in_sizes, int n_in,
                              void* d_out, int out_size, void* d_ws, size_t ws_size,
                              hipStream_t stream) {
  const float* x     = (const float*)d_in[0];
  const float* w1    = (const float*)d_in[1];
  const float* b1    = (const float*)d_in[2];
  const float* w2    = (const float*)d_in[3];
  const float* b2    = (const float*)d_in[4];
  const float* w_ih0 = (const float*)d_in[5];
  const float* w_hh0 = (const float*)d_in[6];
  const float* b_ih0 = (const float*)d_in[7];
  const float* b_hh0 = (const float*)d_in[8];
  const float* w_ih1 = (const float*)d_in[9];
  const float* w_hh1 = (const float*)d_in[10];
  const float* b_ih1 = (const float*)d_in[11];
  const float* b_hh1 = (const float*)d_in[12];
  const float* w_out = (const float*)d_in[13];
  const float* b_out = (const float*)d_in[14];
  float* out = (float*)d_out;

  char* ws = (char*)d_ws;
  int*   flags   = (int*)  (ws + 0);                  // 256 B (memset); hdone at byte 128
  float* outst   = (float*)(ws + 256);                // 80 B
  float* xproj0  = (float*)(ws + 4096);               // 4 KB
  float* hs0     = (float*)(ws + 278528);             // 2*4096*128*4 = 4 MB
  float* h1s     = (float*)(ws + 278528 + 4194304);   // 4 MB
  float* xproj1  = (float*)(ws + 278528 + 8388608);   // 4 MB

  hipMemsetAsync(flags, 0, 256, stream);
  k_all<<<NBLK, 512, 0, stream>>>(x, w1, b1, w2, b2, w_ih0, b_ih0, b_hh0,
                                  w_hh0, w_hh1, w_ih1, b_ih1, b_hh1, w_out, b_out,
                                  flags, outst, xproj0, hs0, h1s, xproj1, out);
}

// Round 17
// 61.520 us; speedup vs baseline: 2.8139x; 2.8139x over previous
//
#include <hip/hip_runtime.h>

#define T_STEPS 144000
#define HDIM 128
#define G4 512
#define NB 10
#define CH 16
#define EPS 1e-2f
#define WIN 2
#define SENT 0x7fffffff
#define RING0 4096
#define R0M (RING0-1)
#define RING1 1024
#define R1M (RING1-1)

typedef _Float16 h2f __attribute__((ext_vector_type(2)));

__device__ __forceinline__ float fdot2_(h2f a, h2f b, float c){
#if __has_builtin(__builtin_amdgcn_fdot2)
  return __builtin_amdgcn_fdot2(a, b, c, false);
#else
  float d;
  asm("v_dot2_f32_f16 %0, %1, %2, %3" : "=v"(d) : "v"(a), "v"(b), "v"(c));
  return d;
#endif
}
__device__ __forceinline__ h2f pack2(float x, float y){ h2f r; r[0]=(_Float16)x; r[1]=(_Float16)y; return r; }
__device__ __forceinline__ h2f bc(float f){ return __builtin_bit_cast(h2f, f); }

__device__ __forceinline__ float sigf(float x){ return 1.f/(1.f+__expf(-x)); }
__device__ __forceinline__ float tanh_(float x){
  float e2 = __expf(-2.f*fabsf(x));
  float r = (1.f - e2)/(1.f + e2);
  return copysignf(r, x);
}

// LDS-only barrier: skips the vmcnt(0) drain __syncthreads() would do.
#define FAST_BAR() do { \
  asm volatile("s_waitcnt lgkmcnt(0)" ::: "memory"); \
  __builtin_amdgcn_s_barrier(); \
  asm volatile("" ::: "memory"); \
} while (0)

// 8-accumulator fp16 dot2 matvec body (128-dim row dot)
#define MATVEC8(WH, H4, A0INIT)                                   \
  float a0 = (A0INIT), a1 = 0.f, a2 = 0.f, a3 = 0.f,              \
        a4 = 0.f, a5 = 0.f, a6 = 0.f, a7 = 0.f;                   \
  _Pragma("unroll")                                               \
  for (int k = 0; k < 8; k++) {                                   \
    float4 hv0 = (H4)[2*k], hv1 = (H4)[2*k+1];                    \
    a0 = fdot2_((WH)[8*k+0], bc(hv0.x), a0);                      \
    a1 = fdot2_((WH)[8*k+1], bc(hv0.y), a1);                      \
    a2 = fdot2_((WH)[8*k+2], bc(hv0.z), a2);                      \
    a3 = fdot2_((WH)[8*k+3], bc(hv0.w), a3);                      \
    a4 = fdot2_((WH)[8*k+4], bc(hv1.x), a4);                      \
    a5 = fdot2_((WH)[8*k+5], bc(hv1.y), a5);                      \
    a6 = fdot2_((WH)[8*k+6], bc(hv1.z), a6);                      \
    a7 = fdot2_((WH)[8*k+7], bc(hv1.w), a7);                      \
  }                                                               \
  float pre = ((a0+a1)+(a2+a3)) + ((a4+a5)+(a6+a7));

// flags (ints): [0,1]=prog0 [2,3]=T0p1 [4..7]=progP [8,9]=progC [10,11]=T1p1
//               [12,13]=progH [16]=prepCnt
__global__ __launch_bounds__(512) void k23_fused(
    const float* __restrict__ x, const float* __restrict__ w1, const float* __restrict__ b1,
    const float* __restrict__ w2, const float* __restrict__ b2,
    const float* __restrict__ w_ih0, const float* __restrict__ b_ih0, const float* __restrict__ b_hh0,
    const float* __restrict__ w_hh0, const float* __restrict__ w_hh1,
    const float* __restrict__ w_ih1,
    const float* __restrict__ b_ih1, const float* __restrict__ b_hh1,
    const float* __restrict__ w_out, const float* __restrict__ b_out,
    int* __restrict__ flags, float* __restrict__ outst, float* __restrict__ xproj0,
    float* __restrict__ hs0, float* __restrict__ h1s,
    float* __restrict__ xproj1, float* __restrict__ out)
{
  __shared__ __align__(16) float gls[G4];
  __shared__ __align__(16) _Float16 hls16[HDIM];
  __shared__ __align__(16) float s0ls[CH*HDIM];
  __shared__ float lat1[2][64];
  __shared__ __align__(16) float lat2[2][128];
  __shared__ int okw[2];
  __shared__ int ipc[4];
  const int blk = blockIdx.x;
  const int j = threadIdx.x;
  const int gt = j >> 7;
  int* prog0 = flags + 0; int* T0p1 = flags + 2; int* progP = flags + 4;
  int* progC = flags + 8; int* T1p1 = flags + 10; int* progH = flags + 12;
  int* pcnt = flags + 16;

  if (blk < 32) {
    // ===================== prep: encoder MLP + xproj0, then EXIT (no spinning) ==========
    if (j < 128) {
      int b = j >> 6, jj = j & 63;
      float a = b1[jj];
      #pragma unroll
      for (int k = 0; k < 16; k++) a += x[b*16+k] * w1[jj*16+k];
      lat1[b][jj] = fmaxf(a, 0.f);
    }
    __syncthreads();
    if (j < 256) {
      int b = j >> 7, jj = j & 127;
      float a = b2[jj];
      #pragma unroll
      for (int k = 0; k < 64; k++) a += lat1[b][k] * w2[jj*64+k];
      lat2[b][jj] = fmaxf(a, 0.f);
    }
    __syncthreads();
    if (j < 256) {
      const int rid = blk*32 + (j >> 3);        // 0..1023
      const int b = rid >> 9, r = rid & 511, l8 = j & 7;
      const float4* wv = (const float4*)(w_ih0 + r*128 + l8*16);
      const float4* lv = (const float4*)(&lat2[b][l8*16]);
      float a = 0.f;
      #pragma unroll
      for (int q = 0; q < 4; q++) {
        float4 w = wv[q], l = lv[q];
        a += w.x*l.x + w.y*l.y + w.z*l.z + w.w*l.w;
      }
      a += __shfl_xor(a, 1, 8);
      a += __shfl_xor(a, 2, 8);
      a += __shfl_xor(a, 4, 8);
      if (l8 == 0) xproj0[b*G4 + r] = a + b_ih0[r] + b_hh0[r];
    }
    __syncthreads();                            // drain xproj0 stores
    if (j == 0) __hip_atomic_fetch_add(pcnt, 1, __ATOMIC_RELEASE, __HIP_MEMORY_SCOPE_AGENT);
    return;
  } else if (blk < 34) {
    // ===================== layer-0 producer =====================
    const int b = blk - 32;
    h2f wh[64];
    {
      const float4* wr = (const float4*)(w_hh0 + j*128);
      #pragma unroll
      for (int k = 0; k < 32; k++) {
        float4 w = wr[k];
        wh[2*k]   = pack2(w.x, w.y);
        wh[2*k+1] = pack2(w.z, w.w);
      }
    }
    if (j == 0) {
      while (__hip_atomic_load(pcnt, __ATOMIC_ACQUIRE, __HIP_MEMORY_SCOPE_AGENT) < 32)
        __builtin_amdgcn_s_sleep(2);
    }
    __syncthreads();
    const float xp = xproj0[b*G4 + j];
    float* hb = hs0 + (size_t)b * RING0 * HDIM;
    if (j < HDIM) hls16[j] = (_Float16)0.f;
    float c = 0.f, hp = 0.f;
    int cnt = 0;
    __syncthreads();
    int t = 0;
    for (; t < T_STEPS; ++t) {
      const float4* h4 = (const float4*)hls16;
      MATVEC8(wh, h4, xp)
      gls[j] = (gt == 2) ? tanh_(pre) : sigf(pre);
      FAST_BAR();                                        // bar1 (LDS-only)
      float nh_reg = 0.f;
      if (j < HDIM) {
        float ii = gls[j], ff = gls[128+j], gg = gls[256+j], oo = gls[384+j];
        float nc = ff*c + ii*gg;
        float nh = oo*tanh_(nc);
        bool ok = fabsf(nh-hp) <= EPS && fabsf(nc-c) <= EPS*fmaxf(1.f, fabsf(nc));
        c = nc; hp = nh;
        hls16[j] = (_Float16)nh;
        nh_reg = nh;
        unsigned long long bal = __ballot(ok);
        if ((j & 63) == 0) okw[j >> 6] = (bal == ~0ull) ? 1 : 0;
      }
      FAST_BAR();                                        // bar2 (LDS-only)
      if (j < HDIM) hb[(t & R0M)*HDIM + j] = nh_reg;     // drained at chunk barrier
      cnt = (okw[0] && okw[1]) ? cnt + 1 : 0;
      bool conv = (cnt >= WIN);
      if (((t & (CH-1)) == (CH-1)) && !conv) {
        __syncthreads();                                 // FULL: drains chunk's hb stores
        if (j == 0) {
          __hip_atomic_store(&prog0[b], t+1, __ATOMIC_RELEASE, __HIP_MEMORY_SCOPE_AGENT);
          for (;;) {
            int lo = __hip_atomic_load(&progP[2*b+0], __ATOMIC_ACQUIRE, __HIP_MEMORY_SCOPE_AGENT);
            int hi = __hip_atomic_load(&progP[2*b+1], __ATOMIC_ACQUIRE, __HIP_MEMORY_SCOPE_AGENT);
            int mp = min(lo, hi);
            if ((t + 1 + CH) - mp <= RING0) break;
            __builtin_amdgcn_s_sleep(2);
          }
        }
      }
      if (conv) { ++t; break; }
    }
    __syncthreads();                                     // FULL: drain final stores
    if (j == 0) {
      __hip_atomic_store(&prog0[b], t, __ATOMIC_RELEASE, __HIP_MEMORY_SCOPE_AGENT);
      __hip_atomic_store(&T0p1[b], t+1, __ATOMIC_RELEASE, __HIP_MEMORY_SCOPE_AGENT);
    }
  } else if (blk < 38) {
    // ===================== projector (4 blocks: 2 per batch, reg weights, f32) ==========
    const int pblk = blk - 34;
    const int b = pblk >> 1, half = pblk & 1;
    const int lr = j >> 1, hf2 = j & 1;
    const int row = half*256 + lr;
    float4 wp[16];
    const float4* wr = (const float4*)(w_ih1 + row*128 + hf2*64);
    #pragma unroll
    for (int k = 0; k < 16; k++) wp[k] = wr[k];
    const float biasr = (hf2 == 0) ? (b_ih1[row] + b_hh1[row]) : 0.f;
    const float* hb = hs0 + (size_t)b * RING0 * HDIM;
    float* xp1b = xproj1 + (size_t)b * RING1 * G4;
    int t = 0;
    for (;;) {
      if (j == 0) {
        int av, tv;
        for (;;) {
          av = __hip_atomic_load(&prog0[b], __ATOMIC_ACQUIRE, __HIP_MEMORY_SCOPE_AGENT);
          tv = __hip_atomic_load(&T0p1[b], __ATOMIC_ACQUIRE, __HIP_MEMORY_SCOPE_AGENT);
          int T0v = (tv == 0) ? SENT : tv - 1;
          if (T0v != SENT && t >= T0v) break;
          int need = t + CH; if (T0v != SENT && T0v < need) need = T0v;
          int cons = __hip_atomic_load(&progC[b], __ATOMIC_ACQUIRE, __HIP_MEMORY_SCOPE_AGENT);
          if (av >= need && need <= cons + RING1) break;
          __builtin_amdgcn_s_sleep(2);
        }
        ipc[0] = av; ipc[1] = tv;
      }
      __syncthreads();
      int av = ipc[0], tv = ipc[1];
      int T0v = (tv == 0) ? SENT : tv - 1;
      if (T0v != SENT && t >= T0v) break;
      int lim = (T0v != SENT && T0v < av) ? T0v : av;
      int C = min(CH, lim - t);
      for (int idx = j; idx < CH*HDIM; idx += 512) {
        int cc = idx >> 7, lane = idx & 127;
        float v = 0.f;
        if (cc < C) v = hb[((t + cc) & R0M)*HDIM + lane];
        s0ls[idx] = v;
      }
      __syncthreads();
      float xpa[CH];
      #pragma unroll
      for (int cc = 0; cc < CH; cc++) xpa[cc] = 0.f;
      #pragma unroll
      for (int k = 0; k < 16; k++) {
        float4 w = wp[k];
        const float4* sp = ((const float4*)s0ls) + hf2*16 + k;
        #pragma unroll
        for (int cc = 0; cc < CH; cc++) {
          if (cc >= C) break;
          float4 sv = sp[cc*32];
          xpa[cc] += w.x*sv.x + w.y*sv.y + w.z*sv.z + w.w*sv.w;
        }
      }
      #pragma unroll
      for (int cc = 0; cc < CH; cc++) {
        if (cc >= C) break;
        float v = xpa[cc] + biasr;
        v += __shfl_xor(v, 1, 2);
        if (hf2 == 0) xp1b[((t + cc) & R1M)*G4 + row] = v;
      }
      __syncthreads();                                   // FULL: drains xp1b stores
      if (j == 0) {
        __hip_atomic_store(&progP[2*b + half], t + C, __ATOMIC_RELEASE, __HIP_MEMORY_SCOPE_AGENT);
      }
      t += C;
    }
  } else if (blk < 40) {
    // ===================== layer-1 consumer =====================
    const int b = blk - 38;
    h2f wh[64];
    {
      const float4* wr = (const float4*)(w_hh1 + j*128);
      #pragma unroll
      for (int k = 0; k < 32; k++) {
        float4 w = wr[k];
        wh[2*k]   = pack2(w.x, w.y);
        wh[2*k+1] = pack2(w.z, w.w);
      }
    }
    const float* hb = hs0 + (size_t)b * RING0 * HDIM;
    float* h1b = h1s + (size_t)b * RING0 * HDIM;
    const float* xp1b = xproj1 + (size_t)b * RING1 * G4;
    if (j < HDIM) hls16[j] = (_Float16)0.f;
    float c = 0.f, hp = 0.f;
    int cnt = 0;
    __syncthreads();
    int t = 0, T0fin = T_STEPS;

    // -------- Phase A: t < T0, input from xproj1 ring --------
    for (;;) {
      if (j == 0) {
        int pv, tv;
        for (;;) {
          int lo = __hip_atomic_load(&progP[2*b+0], __ATOMIC_ACQUIRE, __HIP_MEMORY_SCOPE_AGENT);
          int hi = __hip_atomic_load(&progP[2*b+1], __ATOMIC_ACQUIRE, __HIP_MEMORY_SCOPE_AGENT);
          pv = min(lo, hi);
          tv = __hip_atomic_load(&T0p1[b], __ATOMIC_ACQUIRE, __HIP_MEMORY_SCOPE_AGENT);
          int T0v = (tv == 0) ? SENT : tv - 1;
          if (T0v != SENT && t >= T0v) break;
          int need = t + CH; if (T0v != SENT && T0v < need) need = T0v;
          int ph = __hip_atomic_load(&progH[b], __ATOMIC_ACQUIRE, __HIP_MEMORY_SCOPE_AGENT);
          if (pv >= need && need - ph <= RING0) break;
          __builtin_amdgcn_s_sleep(2);
        }
        ipc[2] = pv; ipc[3] = tv;
      }
      __syncthreads();
      int pv = ipc[2], tv = ipc[3];
      int T0v = (tv == 0) ? SENT : tv - 1;
      if (T0v != SENT && t >= T0v) { T0fin = T0v; break; }
      int lim = (T0v != SENT && T0v < pv) ? T0v : pv;
      int C = min(CH, lim - t);
      float xpa[CH];
      #pragma unroll
      for (int cc = 0; cc < CH; cc++) {
        if (cc >= C) break;
        xpa[cc] = xp1b[((t + cc) & R1M)*G4 + j];
      }
      for (int cc = 0; cc < C; cc++) {
        const float4* h4 = (const float4*)hls16;
        MATVEC8(wh, h4, xpa[cc])
        gls[j] = (gt == 2) ? tanh_(pre) : sigf(pre);
        FAST_BAR();                                      // bar1 (LDS-only)
        float nh_reg = 0.f;
        if (j < HDIM) {
          float ii = gls[j], ff = gls[128+j], gg = gls[256+j], oo = gls[384+j];
          float nc = ff*c + ii*gg;
          float nh = oo*tanh_(nc);
          c = nc; hp = nh;
          hls16[j] = (_Float16)nh;
          nh_reg = nh;
        }
        FAST_BAR();                                      // bar2 (LDS-only)
        if (j < HDIM) h1b[((t + cc) & R0M)*HDIM + j] = nh_reg;  // drained at chunk barrier
      }
      __syncthreads();                                   // FULL: drains chunk's h1 stores
      if (j == 0) {
        __hip_atomic_store(&progC[b], t + C, __ATOMIC_RELEASE, __HIP_MEMORY_SCOPE_AGENT);
      }
      t += C;
    }

    // -------- Phase B: constant input, convergence detect --------
    if (T0fin < T_STEPS) {
      if (j < HDIM) s0ls[j] = hb[((T0fin-1) & R0M)*HDIM + j];
      __syncthreads();
      float xb = b_ih1[j] + b_hh1[j];
      {
        const float4* wi = (const float4*)(w_ih1 + j*128);
        const float4* s04 = (const float4*)s0ls;
        #pragma unroll
        for (int k = 0; k < 32; k++) {
          float4 w = wi[k], sv = s04[k];
          xb += w.x*sv.x + w.y*sv.y + w.z*sv.z + w.w*sv.w;
        }
      }
      for (; t < T_STEPS; ++t) {
        const float4* h4 = (const float4*)hls16;
        MATVEC8(wh, h4, xb)
        gls[j] = (gt == 2) ? tanh_(pre) : sigf(pre);
        FAST_BAR();                                      // bar1 (LDS-only)
        float nh_reg = 0.f;
        if (j < HDIM) {
          float ii = gls[j], ff = gls[128+j], gg = gls[256+j], oo = gls[384+j];
          float nc = ff*c + ii*gg;
          float nh = oo*tanh_(nc);
          bool ok = fabsf(nh-hp) <= EPS && fabsf(nc-c) <= EPS*fmaxf(1.f, fabsf(nc));
          c = nc; hp = nh;
          hls16[j] = (_Float16)nh;
          nh_reg = nh;
          unsigned long long bal = __ballot(ok);
          if ((j & 63) == 0) okw[j >> 6] = (bal == ~0ull) ? 1 : 0;
        }
        FAST_BAR();                                      // bar2 (LDS-only)
        if (j < HDIM) h1b[(t & R0M)*HDIM + j] = nh_reg;  // drained at chunk barrier
        cnt = (okw[0] && okw[1]) ? cnt + 1 : 0;
        bool conv = (cnt >= WIN);
        if (((t & (CH-1)) == (CH-1)) && !conv) {
          __syncthreads();                               // FULL: drains chunk's h1 stores
          if (j == 0) {
            __hip_atomic_store(&progC[b], t+1, __ATOMIC_RELEASE, __HIP_MEMORY_SCOPE_AGENT);
            for (;;) {
              int ph = __hip_atomic_load(&progH[b], __ATOMIC_ACQUIRE, __HIP_MEMORY_SCOPE_AGENT);
              if ((t + 1 + CH) - ph <= RING0) break;
              __builtin_amdgcn_s_sleep(2);
            }
          }
        }
        if (conv) { ++t; break; }
      }
    }
    __syncthreads();                                     // FULL: drain final h1 stores
    if (j == 0) {
      __hip_atomic_store(&progC[b], t, __ATOMIC_RELEASE, __HIP_MEMORY_SCOPE_AGENT);
      __hip_atomic_store(&T1p1[b], t + 1, __ATOMIC_RELEASE, __HIP_MEMORY_SCOPE_AGENT);
    }
  } else {
    // ===================== head (2 blocks): out = w_out . h1 + b_out =====================
    const int b = blk - 40;
    const float* h1b = h1s + (size_t)b * RING0 * HDIM;
    float* outb = out + (size_t)b * T_STEPS * NB;
    const int n = (j < 160) ? (j >> 4) : 0;   // band 0..9
    const int cc16 = j & 15;                  // step-in-chunk
    float4 wo4[32];
    if (j < 160) {
      const float4* wv = (const float4*)(w_out + n*HDIM);
      #pragma unroll
      for (int k = 0; k < 32; k++) wo4[k] = wv[k];
    }
    const float bo = (j < 160) ? b_out[n] : 0.f;
    int t = 0, T1fin = -1;
    for (;;) {
      if (j == 0) {
        int pc, tv;
        for (;;) {
          pc = __hip_atomic_load(&progC[b], __ATOMIC_ACQUIRE, __HIP_MEMORY_SCOPE_AGENT);
          tv = __hip_atomic_load(&T1p1[b], __ATOMIC_ACQUIRE, __HIP_MEMORY_SCOPE_AGENT);
          if (tv != 0 || pc >= t + 1) break;
          __builtin_amdgcn_s_sleep(2);
        }
        ipc[0] = pc; ipc[1] = tv;
      }
      __syncthreads();
      int pc = ipc[0], tv = ipc[1];
      int T1v = (tv == 0) ? SENT : tv - 1;
      int lim = (T1v != SENT && T1v < pc) ? T1v : pc;
      while (t < lim) {
        int C = min(CH, lim - t);
        if (j < 160 && cc16 < C) {
          const float4* hv4 = (const float4*)(h1b + (size_t)((t + cc16) & R0M)*HDIM);
          float a0 = 0.f, a1 = 0.f, a2 = 0.f, a3 = 0.f;
          #pragma unroll
          for (int k = 0; k < 32; k++) {
            float4 h = hv4[k], w = wo4[k];
            a0 += w.x*h.x; a1 += w.y*h.y; a2 += w.z*h.z; a3 += w.w*h.w;
          }
          outb[(size_t)(t + cc16)*NB + n] = (a0+a1)+(a2+a3) + bo;
        }
        t += C;
      }
      __syncthreads();
      if (j == 0) __hip_atomic_store(&progH[b], t, __ATOMIC_RELEASE, __HIP_MEMORY_SCOPE_AGENT);
      if (T1v != SENT && t >= T1v) { T1fin = T1v; break; }
    }
    // outstar from h1[T1-1]
    if (j < 10) {
      const float4* hv4 = (const float4*)(h1b + (size_t)((T1fin - 1) & R0M)*HDIM);
      const float4* wv = (const float4*)(w_out + j*HDIM);
      float a0 = 0.f, a1 = 0.f, a2 = 0.f, a3 = 0.f;
      #pragma unroll
      for (int k = 0; k < 32; k++) {
        float4 h = hv4[k], w = wv[k];
        a0 += w.x*h.x; a1 += w.y*h.y; a2 += w.z*h.z; a3 += w.w*h.w;
      }
      outst[b*NB + j] = (a0+a1)+(a2+a3) + b_out[j];
    }
  }
}

// ---------------- K4: fill t >= T1 with out* ----------------
__global__ __launch_bounds__(256) void k4_fill(const int* __restrict__ T1p1,
                                               const float* __restrict__ outst,
                                               float* __restrict__ out)
{
  const int total = 2*T_STEPS*NB;
  const int T1a = T1p1[0] - 1, T1b = T1p1[1] - 1;
  for (int idx = blockIdx.x*256 + threadIdx.x; idx < total; idx += 4096*256) {
    int n = idx % NB;
    int bt = idx / NB;
    int t = bt % T_STEPS;
    int b = bt / T_STEPS;
    if (t >= (b ? T1b : T1a)) out[idx] = outst[b*NB + n];
  }
}

extern "C" void kernel_launch(void* const* d_in, const int* in_sizes, int n_in,
                              void* d_out, int out_size, void* d_ws, size_t ws_size,
                              hipStream_t stream) {
  const float* x     = (const float*)d_in[0];
  const float* w1    = (const float*)d_in[1];
  const float* b1    = (const float*)d_in[2];
  const float* w2    = (const float*)d_in[3];
  const float* b2    = (const float*)d_in[4];
  const float* w_ih0 = (const float*)d_in[5];
  const float* w_hh0 = (const float*)d_in[6];
  const float* b_ih0 = (const float*)d_in[7];
  const float* b_hh0 = (const float*)d_in[8];
  const float* w_ih1 = (const float*)d_in[9];
  const float* w_hh1 = (const float*)d_in[10];
  const float* b_ih1 = (const float*)d_in[11];
  const float* b_hh1 = (const float*)d_in[12];
  const float* w_out = (const float*)d_in[13];
  const float* b_out = (const float*)d_in[14];
  float* out = (float*)d_out;

  char* ws = (char*)d_ws;
  int*   flags   = (int*)  (ws + 0);                  // 96 B (memset)
  float* outst   = (float*)(ws + 128);                // 80 B
  float* xproj0  = (float*)(ws + 4096);               // 4 KB
  float* hs0     = (float*)(ws + 278528);             // 2*4096*128*4 = 4 MB
  float* h1s     = (float*)(ws + 278528 + 4194304);   // 4 MB
  float* xproj1  = (float*)(ws + 278528 + 8388608);   // 4 MB

  hipMemsetAsync(flags, 0, 96, stream);
  k23_fused<<<42, 512, 0, stream>>>(x, w1, b1, w2, b2, w_ih0, b_ih0, b_hh0,
                                    w_hh0, w_hh1, w_ih1, b_ih1, b_hh1, w_out, b_out,
                                    flags, outst, xproj0, hs0, h1s, xproj1, out);
  k4_fill<<<4096, 256, 0, stream>>>(flags + 10, outst, out);
}